// Round 1
// baseline (449.327 us; speedup 1.0000x reference)
//
#include <hip/hip_runtime.h>
#include <math.h>

#define NB 32
#define NT 512
#define NS 64
#define NOBS 4
#define NEMB 32
#define NPE 16
#define NATTN 10
#define ND 26  // ATTN + PE

// obs_emb_weights LDS layout: 64 rows (sensor s) x 128 dwords (o*32+e),
// 16B-chunk XOR swizzle so per-lane ds_read_b128 of row s spreads banks.
__device__ __forceinline__ int obs_idx(int s, int chunk) {
    return (s << 7) + (((chunk ^ (s & 7)) & 31) << 2);
}

__global__ __launch_bounds__(512)
void raindrop_kernel(const float* __restrict__ x,
                     const float* __restrict__ times,
                     const float* __restrict__ mask,
                     const float* __restrict__ obsW,
                     const float* __restrict__ attnW,
                     const float* __restrict__ recvW,
                     const float* __restrict__ recvB,
                     float* __restrict__ out)
{
    __shared__ float w_lds[NS * 128];  // 32 KiB

    const int tid = threadIdx.x;

    // Stage S*OBS*EMB = 8192 floats into LDS (coalesced global float4 reads,
    // swizzled LDS writes). 512 threads x 4 iters x 4 floats.
#pragma unroll
    for (int k = 0; k < 4; ++k) {
        int i = (tid << 2) + (k << 11);
        float4 v = *reinterpret_cast<const float4*>(obsW + i);
        int s = i >> 7;
        int c = (i & 127) >> 2;
        *reinterpret_cast<float4*>(&w_lds[obs_idx(s, c)]) = v;
    }

    const int lane = tid & 63;
    const int wv = tid >> 6;
    const int bt = blockIdx.x * 8 + wv;   // one wave per (b,t)
    const int s = lane;                   // lane = sensor

    // positional encoding (wave-uniform; div[i] = 10000^(-i/8) = 10^(-i/2))
    const float tt = times[bt];
    const float divs[8] = {1.0f, 0.31622776601683794f, 0.1f, 0.031622776601683794f,
                           0.01f, 0.0031622776601683794f, 0.001f, 0.00031622776601683794f};
    float pe[NPE];
#pragma unroll
    for (int i = 0; i < 8; ++i) {
        float sv, cv;
        sincosf(tt * divs[i], &sv, &cv);
        pe[2 * i]     = sv;
        pe[2 * i + 1] = cv;
    }

    // per-lane inputs (coalesced: 64 lanes x 16B contiguous)
    const float4 xv = *reinterpret_cast<const float4*>(x + ((size_t)bt * NS + s) * NOBS);
    const float  mv = mask[(size_t)bt * NS + s];

    __syncthreads();

    // hq[d] = recv_b[d] + sum_e h_e * recv_W[e][d],
    // h_e = relu(sum_o x_o * obsW[s][o][e]) * mask
    float hq[ND];
#pragma unroll
    for (int d = 0; d < ND; ++d) hq[d] = recvB[d];  // uniform -> s_load

#pragma unroll
    for (int eb = 0; eb < 8; ++eb) {  // e = eb*4 + j
        float a0 = 0.f, a1 = 0.f, a2 = 0.f, a3 = 0.f;
        {
            float4 w0 = *reinterpret_cast<const float4*>(&w_lds[obs_idx(s, 0 * 8 + eb)]);
            a0 += xv.x * w0.x; a1 += xv.x * w0.y; a2 += xv.x * w0.z; a3 += xv.x * w0.w;
            float4 w1 = *reinterpret_cast<const float4*>(&w_lds[obs_idx(s, 1 * 8 + eb)]);
            a0 += xv.y * w1.x; a1 += xv.y * w1.y; a2 += xv.y * w1.z; a3 += xv.y * w1.w;
            float4 w2 = *reinterpret_cast<const float4*>(&w_lds[obs_idx(s, 2 * 8 + eb)]);
            a0 += xv.z * w2.x; a1 += xv.z * w2.y; a2 += xv.z * w2.z; a3 += xv.z * w2.w;
            float4 w3 = *reinterpret_cast<const float4*>(&w_lds[obs_idx(s, 3 * 8 + eb)]);
            a0 += xv.w * w3.x; a1 += xv.w * w3.y; a2 += xv.w * w3.z; a3 += xv.w * w3.w;
        }
        const float h0 = fmaxf(a0, 0.f) * mv;
        const float h1 = fmaxf(a1, 0.f) * mv;
        const float h2 = fmaxf(a2, 0.f) * mv;
        const float h3 = fmaxf(a3, 0.f) * mv;
        const float* rw = recvW + (eb * 4) * ND;  // uniform base -> s_load
#pragma unroll
        for (int d = 0; d < ND; ++d) {
            hq[d] += h0 * rw[d] + h1 * rw[ND + d] + h2 * rw[2 * ND + d] + h3 * rw[3 * ND + d];
        }
    }

    // u-independent PE dot (recv_b part folded in via hq init)
    float beta = 0.f;
#pragma unroll
    for (int p = 0; p < NPE; ++p) beta += hq[NATTN + p] * pe[p];

    // alpha[s][u] = relu(beta + sum_a hq[a] * attnW[u][a]); lane writes its
    // contiguous 256B output row as 4x dwordx4.
    float* orow = out + (size_t)bt * (NS * NS) + (size_t)s * NS;
#pragma unroll 4
    for (int u0 = 0; u0 < NS; u0 += 4) {
        float r[4];
#pragma unroll
        for (int j = 0; j < 4; ++j) {
            const float* aw = attnW + (u0 + j) * NATTN;  // uniform -> s_load
            float acc = beta;
#pragma unroll
            for (int q = 0; q < NATTN; ++q) acc += hq[q] * aw[q];
            r[j] = fmaxf(acc, 0.f);
        }
        float4 rv;
        rv.x = r[0]; rv.y = r[1]; rv.z = r[2]; rv.w = r[3];
        *reinterpret_cast<float4*>(orow + u0) = rv;
    }
}

extern "C" void kernel_launch(void* const* d_in, const int* in_sizes, int n_in,
                              void* d_out, int out_size, void* d_ws, size_t ws_size,
                              hipStream_t stream) {
    const float* x     = (const float*)d_in[0];
    const float* times = (const float*)d_in[1];
    const float* mask  = (const float*)d_in[2];
    const float* obsW  = (const float*)d_in[3];
    const float* attnW = (const float*)d_in[4];
    const float* recvW = (const float*)d_in[5];
    const float* recvB = (const float*)d_in[6];
    float* out = (float*)d_out;

    // B*T = 16384 (b,t) pairs, one wave each, 8 waves per block
    raindrop_kernel<<<dim3((NB * NT) / 8), dim3(512), 0, stream>>>(
        x, times, mask, obsW, attnW, recvW, recvB, out);
}

// Round 2
// 80.236 us; speedup vs baseline: 5.6000x; 5.6000x over previous
//
#include <hip/hip_runtime.h>
#include <math.h>

#define NB 32
#define NT 512
#define NS 64
#define NOBS 4
#define NEMB 32
#define NPE 16
#define NATTN 10
#define ND 26  // ATTN + PE

// obs_emb_weights LDS layout: 64 rows (sensor s) x 128 dwords (o*32+e),
// 16B-chunk XOR swizzle so per-lane ds_read_b128 of row s spreads banks.
__device__ __forceinline__ int obs_idx(int s, int chunk) {
    return (s << 7) + (((chunk ^ (s & 7)) & 31) << 2);
}

__global__ __launch_bounds__(512)
void raindrop_kernel(const float* __restrict__ x,
                     const float* __restrict__ times,
                     const float* __restrict__ mask,
                     const float* __restrict__ obsW,
                     const float* __restrict__ attnW,
                     const float* __restrict__ recvW,
                     const float* __restrict__ recvB,
                     float* __restrict__ out)
{
    // 32 KiB, reused: phase 1 = swizzled obsW tile; phase 3 = hq rows
    __shared__ float lds[NS * 128];

    const int tid = threadIdx.x;

    // Stage S*OBS*EMB = 8192 floats into LDS (coalesced global float4 reads,
    // swizzled LDS writes). 512 threads x 4 iters x 4 floats.
#pragma unroll
    for (int k = 0; k < 4; ++k) {
        int i = (tid << 2) + (k << 11);
        float4 v = *reinterpret_cast<const float4*>(obsW + i);
        int si = i >> 7;
        int c = (i & 127) >> 2;
        *reinterpret_cast<float4*>(&lds[obs_idx(si, c)]) = v;
    }

    const int lane = tid & 63;
    const int wv = tid >> 6;
    const int bt = blockIdx.x * 8 + wv;   // one wave per (b,t)
    const int s = lane;                   // phase-1 role: lane = sensor

    // per-lane attnW row for phase-3 role u = lane: 10 floats, loaded ONCE
    // into VGPRs (kills the 640 s_load/wave storm of the old u-loop).
    float aW[NATTN];
    {
        const float2* ap = reinterpret_cast<const float2*>(attnW + lane * NATTN);
        float2 a0 = ap[0], a1 = ap[1], a2 = ap[2], a3 = ap[3], a4 = ap[4];
        aW[0] = a0.x; aW[1] = a0.y; aW[2] = a1.x; aW[3] = a1.y; aW[4] = a2.x;
        aW[5] = a2.y; aW[6] = a3.x; aW[7] = a3.y; aW[8] = a4.x; aW[9] = a4.y;
    }

    // positional encoding (wave-uniform; div[i] = 10^(-i/2)); native sin/cos
    const float tt = times[bt];
    const float divs[8] = {1.0f, 0.31622776601683794f, 0.1f, 0.031622776601683794f,
                           0.01f, 0.0031622776601683794f, 0.001f, 0.00031622776601683794f};
    float pe[NPE];
#pragma unroll
    for (int i = 0; i < 8; ++i) {
        float ang = tt * divs[i];
        pe[2 * i]     = __sinf(ang);
        pe[2 * i + 1] = __cosf(ang);
    }

    // per-lane inputs (coalesced: 64 lanes x 16B contiguous)
    const float4 xv = *reinterpret_cast<const float4*>(x + ((size_t)bt * NS + s) * NOBS);
    const float  mv = mask[(size_t)bt * NS + s];

    __syncthreads();  // obsW tile ready

    // hq[d] = recv_b[d] + sum_e h_e * recv_W[e][d],
    // h_e = relu(sum_o x_o * obsW[s][o][e]) * mask
    float hq[ND];
#pragma unroll
    for (int d = 0; d < ND; ++d) hq[d] = recvB[d];  // uniform -> s_load

#pragma unroll
    for (int eb = 0; eb < 8; ++eb) {  // e = eb*4 + j
        float a0 = 0.f, a1 = 0.f, a2 = 0.f, a3 = 0.f;
        {
            float4 w0 = *reinterpret_cast<const float4*>(&lds[obs_idx(s, 0 * 8 + eb)]);
            a0 += xv.x * w0.x; a1 += xv.x * w0.y; a2 += xv.x * w0.z; a3 += xv.x * w0.w;
            float4 w1 = *reinterpret_cast<const float4*>(&lds[obs_idx(s, 1 * 8 + eb)]);
            a0 += xv.y * w1.x; a1 += xv.y * w1.y; a2 += xv.y * w1.z; a3 += xv.y * w1.w;
            float4 w2 = *reinterpret_cast<const float4*>(&lds[obs_idx(s, 2 * 8 + eb)]);
            a0 += xv.z * w2.x; a1 += xv.z * w2.y; a2 += xv.z * w2.z; a3 += xv.z * w2.w;
            float4 w3 = *reinterpret_cast<const float4*>(&lds[obs_idx(s, 3 * 8 + eb)]);
            a0 += xv.w * w3.x; a1 += xv.w * w3.y; a2 += xv.w * w3.z; a3 += xv.w * w3.w;
        }
        const float h0 = fmaxf(a0, 0.f) * mv;
        const float h1 = fmaxf(a1, 0.f) * mv;
        const float h2 = fmaxf(a2, 0.f) * mv;
        const float h3 = fmaxf(a3, 0.f) * mv;
        const float* rw = recvW + (eb * 4) * ND;  // uniform base -> s_load
#pragma unroll
        for (int d = 0; d < ND; ++d) {
            hq[d] += h0 * rw[d] + h1 * rw[ND + d] + h2 * rw[2 * ND + d] + h3 * rw[3 * ND + d];
        }
    }

    // u-independent part: beta_s = recv-PE dot (recv_b folded via hq init)
    float beta = 0.f;
#pragma unroll
    for (int p = 0; p < NPE; ++p) beta += hq[NATTN + p] * pe[p];

    __syncthreads();  // all waves done READING the obsW tile -> safe to reuse

    // Stage this wave's hq rows (wave-private region, 64 rows x 12 floats).
    // Row: hq[0..9], beta, pad. All three 16B chunks are 16B-aligned (48B row).
    float* hbase = &lds[wv * (NS * 12)];
    {
        float* hrow = hbase + s * 12;
        float4 v0 = {hq[0], hq[1], hq[2], hq[3]};
        float4 v1 = {hq[4], hq[5], hq[6], hq[7]};
        float4 v2 = {hq[8], hq[9], beta, 0.f};
        *reinterpret_cast<float4*>(hrow)     = v0;
        *reinterpret_cast<float4*>(hrow + 4) = v1;
        *reinterpret_cast<float4*>(hrow + 8) = v2;
    }
    // No barrier: this wave reads only rows written by its own lanes, and
    // DS ops from one wave complete in program order.

    // Phase 3: lane = u. For each sensor row r: broadcast its hq (uniform
    // ds_read_b128 x3), 10 FMAs vs per-lane aW, one fully-coalesced 256B store.
    float* obase = out + (size_t)bt * (NS * NS) + lane;
#pragma unroll 4
    for (int r = 0; r < NS; ++r) {
        const float* hr = hbase + r * 12;
        float4 h0 = *reinterpret_cast<const float4*>(hr);
        float4 h1 = *reinterpret_cast<const float4*>(hr + 4);
        float4 h2 = *reinterpret_cast<const float4*>(hr + 8);
        float acc = h2.z;  // beta_r
        acc += h0.x * aW[0]; acc += h0.y * aW[1];
        acc += h0.z * aW[2]; acc += h0.w * aW[3];
        acc += h1.x * aW[4]; acc += h1.y * aW[5];
        acc += h1.z * aW[6]; acc += h1.w * aW[7];
        acc += h2.x * aW[8]; acc += h2.y * aW[9];
        obase[r * NS] = fmaxf(acc, 0.f);
    }
}

extern "C" void kernel_launch(void* const* d_in, const int* in_sizes, int n_in,
                              void* d_out, int out_size, void* d_ws, size_t ws_size,
                              hipStream_t stream) {
    const float* x     = (const float*)d_in[0];
    const float* times = (const float*)d_in[1];
    const float* mask  = (const float*)d_in[2];
    const float* obsW  = (const float*)d_in[3];
    const float* attnW = (const float*)d_in[4];
    const float* recvW = (const float*)d_in[5];
    const float* recvB = (const float*)d_in[6];
    float* out = (float*)d_out;

    // B*T = 16384 (b,t) pairs, one wave each, 8 waves per block
    raindrop_kernel<<<dim3((NB * NT) / 8), dim3(512), 0, stream>>>(
        x, times, mask, obsW, attnW, recvW, recvB, out);
}